// Round 1
// baseline (1126.586 us; speedup 1.0000x reference)
//
#include <hip/hip_runtime.h>
#include <hip/hip_bf16.h>
#include <math.h>
#include <stdint.h>

#define N_NODES 40000
#define N_EDGES 640000
#define F_IN    512
#define F_OUT   32
#define HEADS   8
#define C_OUT   (HEADS * F_OUT)   // 256
#define NEG_SLOPE 0.2f
#define EPS_F   1e-16f

// ---------------------------------------------------------------------------
// K1: projection GEMM  h[n][c] = sum_d x[n][d] * W[hh][d][f],  c = hh*32+f
// 16 rows per block, 256 threads (one output column each), x chunk in LDS.
// ---------------------------------------------------------------------------
#define BM 16
#define KC 32

__global__ __launch_bounds__(256) void gemm_proj(const float* __restrict__ x,
                                                 const float* __restrict__ W,
                                                 float* __restrict__ h) {
    __shared__ float xs[BM][KC + 1];   // +1 pad: conflict-free staging writes
    const int n0 = blockIdx.x * BM;
    const int t  = threadIdx.x;
    const int hh = t >> 5;
    const int f  = t & 31;
    const float* Wp = W + hh * (F_IN * F_OUT) + f;

    float acc[BM];
#pragma unroll
    for (int r = 0; r < BM; ++r) acc[r] = 0.f;

    for (int dbase = 0; dbase < F_IN; dbase += KC) {
        __syncthreads();
        // stage 16 rows x 32 cols = 512 floats, 2 per thread, coalesced rows
#pragma unroll
        for (int l = 0; l < 2; ++l) {
            int j = t + l * 256;
            int r = j >> 5;          // j / KC
            int d = j & (KC - 1);
            xs[r][d] = x[(n0 + r) * F_IN + dbase + d];
        }
        __syncthreads();
#pragma unroll 4
        for (int d = 0; d < KC; ++d) {
            float wv = Wp[(dbase + d) * F_OUT];
#pragma unroll
            for (int r = 0; r < BM; ++r) acc[r] += xs[r][d] * wv;
        }
    }
#pragma unroll
    for (int r = 0; r < BM; ++r) h[(n0 + r) * C_OUT + t] = acc[r];
}

// ---------------------------------------------------------------------------
// K2: s_src[n][hh] = sum_f h[n][hh][f]*a_src[hh][f]   (and same for a_dst)
// 8 nodes per block; each 32-lane group handles one node, loops over heads.
// ---------------------------------------------------------------------------
__global__ __launch_bounds__(256) void attn_scores(const float* __restrict__ h,
                                                   const float* __restrict__ a_src,
                                                   const float* __restrict__ a_dst,
                                                   float* __restrict__ s_src,
                                                   float* __restrict__ s_dst) {
    const int t = threadIdx.x;
    const int g = t >> 5;
    const int f = t & 31;
    const int n = blockIdx.x * 8 + g;
    if (n >= N_NODES) return;
#pragma unroll
    for (int hh = 0; hh < HEADS; ++hh) {
        float hv = h[n * C_OUT + hh * F_OUT + f];
        float vs = hv * a_src[hh * F_OUT + f];
        float vd = hv * a_dst[hh * F_OUT + f];
#pragma unroll
        for (int m = 16; m >= 1; m >>= 1) {
            vs += __shfl_xor(vs, m, 64);
            vd += __shfl_xor(vd, m, 64);
        }
        if (f == 0) {
            s_src[n * HEADS + hh] = vs;
            s_dst[n * HEADS + hh] = vd;
        }
    }
}

// monotone float -> uint mapping for atomicMax-based global float max
__device__ __forceinline__ unsigned int float_order(float fv) {
    unsigned int u = __float_as_uint(fv);
    return (u & 0x80000000u) ? ~u : (u | 0x80000000u);
}

// ---------------------------------------------------------------------------
// K3: per-edge logits + LeakyReLU, global max (ordered atomicMax), dst counts
// ---------------------------------------------------------------------------
__global__ __launch_bounds__(256) void edge_pass1(const int* __restrict__ src,
                                                  const int* __restrict__ dst,
                                                  const float* __restrict__ s_src,
                                                  const float* __restrict__ s_dst,
                                                  float* __restrict__ elog,
                                                  int* __restrict__ count,
                                                  unsigned int* __restrict__ gmax) {
    const int e = blockIdx.x * 256 + threadIdx.x;
    float lmax = -3.4e38f;
    if (e < N_EDGES) {
        int s = src[e], d = dst[e];
        const float4* ps = (const float4*)(s_src + s * 8);
        const float4* pd = (const float4*)(s_dst + d * 8);
        float4 a0 = ps[0], a1 = ps[1];
        float4 b0 = pd[0], b1 = pd[1];
        float v[8] = {a0.x + b0.x, a0.y + b0.y, a0.z + b0.z, a0.w + b0.w,
                      a1.x + b1.x, a1.y + b1.y, a1.z + b1.z, a1.w + b1.w};
#pragma unroll
        for (int i = 0; i < 8; ++i) {
            v[i] = v[i] >= 0.f ? v[i] : NEG_SLOPE * v[i];
            lmax = fmaxf(lmax, v[i]);
        }
        float4* po = (float4*)(elog + (size_t)e * 8);
        po[0] = make_float4(v[0], v[1], v[2], v[3]);
        po[1] = make_float4(v[4], v[5], v[6], v[7]);
        atomicAdd(&count[d], 1);
    }
#pragma unroll
    for (int m = 32; m >= 1; m >>= 1) lmax = fmaxf(lmax, __shfl_xor(lmax, m, 64));
    if ((threadIdx.x & 63) == 0) atomicMax(gmax, float_order(lmax));
}

// ---------------------------------------------------------------------------
// K4: single-block exclusive scan of counts -> row_start (and cursor copy)
// ---------------------------------------------------------------------------
__global__ __launch_bounds__(1024) void scan_counts(const int* __restrict__ count,
                                                    int* __restrict__ row_start,
                                                    int* __restrict__ cursor) {
    __shared__ int buf[1024];
    __shared__ int carry_s;
    const int t = threadIdx.x;
    if (t == 0) carry_s = 0;
    __syncthreads();
    for (int base = 0; base < N_NODES; base += 1024) {
        int i = base + t;
        int v = (i < N_NODES) ? count[i] : 0;
        int acc = v;
        buf[t] = acc;
        __syncthreads();
        for (int off = 1; off < 1024; off <<= 1) {
            int add = (t >= off) ? buf[t - off] : 0;
            __syncthreads();
            acc += add;
            buf[t] = acc;
            __syncthreads();
        }
        int excl = carry_s + acc - v;
        if (i < N_NODES) { row_start[i] = excl; cursor[i] = excl; }
        int total = buf[1023];
        __syncthreads();
        if (t == 0) carry_s += total;
        __syncthreads();
    }
}

// ---------------------------------------------------------------------------
// K5: exp(e - M) in place, denominator atomics, CSR scatter of edge ids
// ---------------------------------------------------------------------------
__global__ __launch_bounds__(256) void edge_pass2(const int* __restrict__ dst,
                                                  float* __restrict__ elog,
                                                  const unsigned int* __restrict__ gmax,
                                                  float* __restrict__ denom,
                                                  int* __restrict__ cursor,
                                                  int* __restrict__ edge_ids) {
    const int e = blockIdx.x * 256 + threadIdx.x;
    if (e >= N_EDGES) return;
    unsigned int o = *gmax;
    float M = __uint_as_float((o & 0x80000000u) ? (o & 0x7FFFFFFFu) : ~o);
    int d = dst[e];
    float4* pe = (float4*)(elog + (size_t)e * 8);
    float4 v0 = pe[0], v1 = pe[1];
    float ex[8] = {__expf(v0.x - M), __expf(v0.y - M), __expf(v0.z - M), __expf(v0.w - M),
                   __expf(v1.x - M), __expf(v1.y - M), __expf(v1.z - M), __expf(v1.w - M)};
    pe[0] = make_float4(ex[0], ex[1], ex[2], ex[3]);
    pe[1] = make_float4(ex[4], ex[5], ex[6], ex[7]);
#pragma unroll
    for (int i = 0; i < 8; ++i) atomicAdd(&denom[d * 8 + i], ex[i]);
    int pos = atomicAdd(&cursor[d], 1);
    edge_ids[pos] = e;
}

// ---------------------------------------------------------------------------
// K6: per-dst-node aggregation. One 256-thread block per node; thread t owns
// output channel t (head t>>5). Coalesced 1 KB h-row read per edge.
// ---------------------------------------------------------------------------
__global__ __launch_bounds__(256) void aggregate(const int* __restrict__ src,
                                                 const float* __restrict__ h,
                                                 const float* __restrict__ expv,
                                                 const float* __restrict__ denom,
                                                 const int* __restrict__ row_start,
                                                 const int* __restrict__ count,
                                                 const int* __restrict__ edge_ids,
                                                 const float* __restrict__ bias,
                                                 float* __restrict__ out) {
    const int n = blockIdx.x;
    const int t = threadIdx.x;
    const int hh = t >> 5;
    const float inv_den = 1.0f / (denom[n * 8 + hh] + EPS_F);
    const int start = row_start[n];
    const int cnt   = count[n];
    float acc = 0.f;
    for (int i = 0; i < cnt; ++i) {
        int e = edge_ids[start + i];
        float w = expv[(size_t)e * 8 + hh];
        int s = src[e];
        acc += w * h[(size_t)s * C_OUT + t];
    }
    out[(size_t)n * C_OUT + t] = acc * inv_den + bias[t];
}

// ---------------------------------------------------------------------------
extern "C" void kernel_launch(void* const* d_in, const int* in_sizes, int n_in,
                              void* d_out, int out_size, void* d_ws, size_t ws_size,
                              hipStream_t stream) {
    const float* x      = (const float*)d_in[0];
    const int*   eidx   = (const int*)d_in[1];
    const float* W      = (const float*)d_in[2];
    const float* a_src  = (const float*)d_in[3];
    const float* a_dst  = (const float*)d_in[4];
    const float* bias   = (const float*)d_in[5];
    float* out = (float*)d_out;

    const int* src = eidx;            // edge_index[0]
    const int* dst = eidx + N_EDGES;  // edge_index[1]

    // workspace carve (256B aligned slabs)
    char* p = (char*)d_ws;
    auto carve = [&](size_t bytes) {
        char* r = p;
        p += (bytes + 255) & ~(size_t)255;
        return r;
    };
    float* h         = (float*)carve((size_t)N_NODES * C_OUT * 4);   // 40.96 MB
    float* s_src     = (float*)carve((size_t)N_NODES * HEADS * 4);   // 1.28 MB
    float* s_dst     = (float*)carve((size_t)N_NODES * HEADS * 4);   // 1.28 MB
    float* elog      = (float*)carve((size_t)N_EDGES * HEADS * 4);   // 20.48 MB
    float* denom     = (float*)carve((size_t)N_NODES * HEADS * 4);   // 1.28 MB
    int*   count     = (int*)carve((size_t)N_NODES * 4);
    int*   row_start = (int*)carve((size_t)N_NODES * 4);
    int*   cursor    = (int*)carve((size_t)N_NODES * 4);
    int*   edge_ids  = (int*)carve((size_t)N_EDGES * 4);             // 2.56 MB
    unsigned int* gmax = (unsigned int*)carve(256);

    hipMemsetAsync(count, 0, (size_t)N_NODES * 4, stream);
    hipMemsetAsync(denom, 0, (size_t)N_NODES * HEADS * 4, stream);
    hipMemsetAsync(gmax, 0, 4, stream);

    gemm_proj<<<N_NODES / BM, 256, 0, stream>>>(x, W, h);
    attn_scores<<<N_NODES / 8, 256, 0, stream>>>(h, a_src, a_dst, s_src, s_dst);
    edge_pass1<<<N_EDGES / 256, 256, 0, stream>>>(src, dst, s_src, s_dst, elog, count, gmax);
    scan_counts<<<1, 1024, 0, stream>>>(count, row_start, cursor);
    edge_pass2<<<N_EDGES / 256, 256, 0, stream>>>(dst, elog, gmax, denom, cursor, edge_ids);
    aggregate<<<N_NODES, 256, 0, stream>>>(src, h, elog, denom, row_start, count, edge_ids, bias, out);
}

// Round 2
// 402.448 us; speedup vs baseline: 2.7993x; 2.7993x over previous
//
#include <hip/hip_runtime.h>
#include <hip/hip_bf16.h>
#include <math.h>
#include <stdint.h>

#define N_NODES 40000
#define N_EDGES 640000
#define F_IN    512
#define F_OUT   32
#define HEADS   8
#define C_OUT   (HEADS * F_OUT)   // 256
#define NEG_SLOPE 0.2f
#define EPS_F   1e-16f

typedef __attribute__((ext_vector_type(8))) short short8;
typedef __attribute__((ext_vector_type(4))) short short4v;
typedef __attribute__((ext_vector_type(4))) float float4v;

// round-to-nearest-even fp32 -> bf16 split: f ~= hi + lo (both bf16)
__device__ __forceinline__ void bf16split(float f, unsigned short& hi, unsigned short& lo) {
    unsigned u = __float_as_uint(f);
    unsigned short h = (unsigned short)((u + 0x7FFF + ((u >> 16) & 1)) >> 16);
    float hf = __uint_as_float(((unsigned)h) << 16);
    float r = f - hf;
    unsigned v = __float_as_uint(r);
    lo = (unsigned short)((v + 0x7FFF + ((v >> 16) & 1)) >> 16);
    hi = h;
}

// ---------------------------------------------------------------------------
// K0: pack W[H][F_IN][F_OUT] -> Bp_hi/lo [kt=16][c=256][kk=32] bf16, where
// c = hh*32+f, k = kt*32+kk. Tile-contiguous so GEMM staging is one 16 KB
// coalesced read per K-step.
// ---------------------------------------------------------------------------
__global__ __launch_bounds__(256) void pack_W(const float* __restrict__ W,
                                              unsigned short* __restrict__ Bp_hi,
                                              unsigned short* __restrict__ Bp_lo) {
    int tid = blockIdx.x * 256 + threadIdx.x;   // 256*512 total
    int c = tid >> 9;          // 0..255
    int k = tid & 511;         // 0..511
    int hh = c >> 5, f = c & 31;
    float v = W[hh * (F_IN * F_OUT) + k * F_OUT + f];
    unsigned short hi, lo;
    bf16split(v, hi, lo);
    int out = (k >> 5) * (256 * 32) + c * 32 + (k & 31);
    Bp_hi[out] = hi;
    Bp_lo[out] = lo;
}

// ---------------------------------------------------------------------------
// K1: MFMA projection GEMM. h[40000][256] = x[40000][512] @ B[512][256].
// Split-precision bf16: h = x_hi*B_hi + x_lo*B_hi + x_hi*B_lo (fp32 acc).
// Block: 256 thr = 4 waves; tile 64 rows x 256 cols; K-step 32. Grid 625.
// Wave w owns cols [w*64, w*64+64); frags 4x4 of 16x16.
// ---------------------------------------------------------------------------
#define A_STRIDE 40   // 32 + 8 bf16 pad: row stride 80 B = 20 banks, conflict-free-ish
#define B_STRIDE 40

__global__ __launch_bounds__(256) void gemm_mfma(const float* __restrict__ x,
                                                 const unsigned short* __restrict__ Bp_hi,
                                                 const unsigned short* __restrict__ Bp_lo,
                                                 float* __restrict__ h) {
    __shared__ unsigned short As_hi[64 * A_STRIDE];
    __shared__ unsigned short As_lo[64 * A_STRIDE];
    __shared__ unsigned short Bs_hi[256 * B_STRIDE];
    __shared__ unsigned short Bs_lo[256 * B_STRIDE];

    const int t = threadIdx.x;
    const int wave = t >> 6, lane = t & 63;
    const int lm = lane & 15;   // fragment row/col
    const int lq = lane >> 4;   // quad
    const int n0 = blockIdx.x * 64;

    float4v acc[4][4];
#pragma unroll
    for (int i = 0; i < 4; ++i)
#pragma unroll
        for (int j = 0; j < 4; ++j) acc[i][j] = (float4v){0.f, 0.f, 0.f, 0.f};

    for (int kt = 0; kt < 16; ++kt) {
        __syncthreads();
        // stage A: 64 rows x 32 floats (fp32 -> bf16 hi/lo), 512 float4 loads
#pragma unroll
        for (int l = 0; l < 2; ++l) {
            int j = t + l * 256;
            int row = j >> 3, q = j & 7;
            float4 v = *(const float4*)&x[(size_t)(n0 + row) * F_IN + kt * 32 + q * 4];
            unsigned short h0, h1, h2, h3, l0, l1, l2, l3;
            bf16split(v.x, h0, l0); bf16split(v.y, h1, l1);
            bf16split(v.z, h2, l2); bf16split(v.w, h3, l3);
            int off = row * A_STRIDE + q * 4;
            *(short4v*)&As_hi[off] = (short4v){(short)h0, (short)h1, (short)h2, (short)h3};
            *(short4v*)&As_lo[off] = (short4v){(short)l0, (short)l1, (short)l2, (short)l3};
        }
        // stage B: 256 cols x 32 k bf16 hi+lo, contiguous 16 KB each
        const uint4* gb_hi = (const uint4*)&Bp_hi[(size_t)kt * 256 * 32];
        const uint4* gb_lo = (const uint4*)&Bp_lo[(size_t)kt * 256 * 32];
#pragma unroll
        for (int l = 0; l < 4; ++l) {
            int j = t + l * 256;            // uint4 chunk = 8 bf16
            int c = j >> 2, kk = (j & 3) * 8;
            *(uint4*)&Bs_hi[c * B_STRIDE + kk] = gb_hi[j];
            *(uint4*)&Bs_lo[c * B_STRIDE + kk] = gb_lo[j];
        }
        __syncthreads();

        short8 a_hi[4], a_lo[4], b_hi[4], b_lo[4];
#pragma unroll
        for (int mi = 0; mi < 4; ++mi) {
            int off = (mi * 16 + lm) * A_STRIDE + lq * 8;
            a_hi[mi] = *(const short8*)&As_hi[off];
            a_lo[mi] = *(const short8*)&As_lo[off];
        }
#pragma unroll
        for (int ni = 0; ni < 4; ++ni) {
            int off = (wave * 64 + ni * 16 + lm) * B_STRIDE + lq * 8;
            b_hi[ni] = *(const short8*)&Bs_hi[off];
            b_lo[ni] = *(const short8*)&Bs_lo[off];
        }
#pragma unroll
        for (int mi = 0; mi < 4; ++mi)
#pragma unroll
            for (int ni = 0; ni < 4; ++ni) {
                acc[mi][ni] = __builtin_amdgcn_mfma_f32_16x16x32_bf16(a_hi[mi], b_hi[ni], acc[mi][ni], 0, 0, 0);
                acc[mi][ni] = __builtin_amdgcn_mfma_f32_16x16x32_bf16(a_lo[mi], b_hi[ni], acc[mi][ni], 0, 0, 0);
                acc[mi][ni] = __builtin_amdgcn_mfma_f32_16x16x32_bf16(a_hi[mi], b_lo[ni], acc[mi][ni], 0, 0, 0);
            }
    }
    // C/D layout: col = lane&15, row = (lane>>4)*4 + reg
#pragma unroll
    for (int mi = 0; mi < 4; ++mi)
#pragma unroll
        for (int ni = 0; ni < 4; ++ni)
#pragma unroll
            for (int r = 0; r < 4; ++r) {
                int row = n0 + mi * 16 + lq * 4 + r;
                int col = wave * 64 + ni * 16 + lm;
                h[(size_t)row * C_OUT + col] = acc[mi][ni][r];
            }
}

// ---------------------------------------------------------------------------
// K2: s_src[n][hh] = sum_f h[n][hh][f]*a_src[hh][f] (same for a_dst)
// ---------------------------------------------------------------------------
__global__ __launch_bounds__(256) void attn_scores(const float* __restrict__ h,
                                                   const float* __restrict__ a_src,
                                                   const float* __restrict__ a_dst,
                                                   float* __restrict__ s_src,
                                                   float* __restrict__ s_dst) {
    const int t = threadIdx.x;
    const int g = t >> 5;
    const int f = t & 31;
    const int n = blockIdx.x * 8 + g;
#pragma unroll
    for (int hh = 0; hh < HEADS; ++hh) {
        float hv = h[(size_t)n * C_OUT + hh * F_OUT + f];
        float vs = hv * a_src[hh * F_OUT + f];
        float vd = hv * a_dst[hh * F_OUT + f];
#pragma unroll
        for (int m = 16; m >= 1; m >>= 1) {
            vs += __shfl_xor(vs, m, 64);
            vd += __shfl_xor(vd, m, 64);
        }
        if (f == 0) {
            s_src[n * HEADS + hh] = vs;
            s_dst[n * HEADS + hh] = vd;
        }
    }
}

// ---------------------------------------------------------------------------
// K3: per-dst in-degree counts
// ---------------------------------------------------------------------------
__global__ __launch_bounds__(256) void count_edges(const int* __restrict__ dst,
                                                   int* __restrict__ count) {
    int e = blockIdx.x * 256 + threadIdx.x;
    atomicAdd(&count[dst[e]], 1);
}

// ---------------------------------------------------------------------------
// K4: single-block shfl-based exclusive scan -> row_start, cursor
// ---------------------------------------------------------------------------
__global__ __launch_bounds__(1024) void scan_counts(const int* __restrict__ count,
                                                    int* __restrict__ row_start,
                                                    int* __restrict__ cursor) {
    __shared__ int wsum[16];
    __shared__ int tot_s;
    __shared__ int carry_s;
    const int t = threadIdx.x;
    const int lane = t & 63, wid = t >> 6;
    if (t == 0) carry_s = 0;
    __syncthreads();
    for (int base = 0; base < N_NODES; base += 1024) {
        int i = base + t;
        int v = (i < N_NODES) ? count[i] : 0;
        int inc = v;
#pragma unroll
        for (int d = 1; d < 64; d <<= 1) {
            int u = __shfl_up(inc, d, 64);
            if (lane >= d) inc += u;
        }
        if (lane == 63) wsum[wid] = inc;
        __syncthreads();
        if (t < 16) {
            int s = wsum[t];
            int sc = s;
#pragma unroll
            for (int d = 1; d < 16; d <<= 1) {
                int u = __shfl_up(sc, d, 64);
                if (t >= d) sc += u;
            }
            wsum[t] = sc - s;           // exclusive wave offset
            if (t == 15) tot_s = sc;    // chunk total
        }
        __syncthreads();
        int excl = carry_s + wsum[wid] + inc - v;
        if (i < N_NODES) { row_start[i] = excl; cursor[i] = excl; }
        __syncthreads();
        if (t == 0) carry_s += tot_s;
    }
}

// ---------------------------------------------------------------------------
// K5: scatter. Recompute exp(leaky(e)) (NO global max-shift: alpha is
// shift-invariant up to the +1e-16 eps, relative effect <= ~1e-6) and write
// payload sorted by dst so aggregate reads sequentially.
// ---------------------------------------------------------------------------
__global__ __launch_bounds__(256) void scatter_edges(const int* __restrict__ src,
                                                     const int* __restrict__ dst,
                                                     const float* __restrict__ s_src,
                                                     const float* __restrict__ s_dst,
                                                     int* __restrict__ cursor,
                                                     int* __restrict__ src_sorted,
                                                     float* __restrict__ w_sorted) {
    int e = blockIdx.x * 256 + threadIdx.x;
    int s = src[e], d = dst[e];
    const float4* ps = (const float4*)(s_src + s * 8);
    const float4* pd = (const float4*)(s_dst + d * 8);
    float4 a0 = ps[0], a1 = ps[1];
    float4 b0 = pd[0], b1 = pd[1];
    float v[8] = {a0.x + b0.x, a0.y + b0.y, a0.z + b0.z, a0.w + b0.w,
                  a1.x + b1.x, a1.y + b1.y, a1.z + b1.z, a1.w + b1.w};
#pragma unroll
    for (int i = 0; i < 8; ++i) {
        float lv = v[i] >= 0.f ? v[i] : NEG_SLOPE * v[i];
        v[i] = __expf(lv);
    }
    int pos = atomicAdd(&cursor[d], 1);
    src_sorted[pos] = s;
    float4* po = (float4*)(w_sorted + (size_t)pos * 8);
    po[0] = make_float4(v[0], v[1], v[2], v[3]);
    po[1] = make_float4(v[4], v[5], v[6], v[7]);
}

// ---------------------------------------------------------------------------
// K6: per-dst aggregation; denominator computed inline; bias fused.
// Block per node, thread t owns channel t (head t>>5). src ids prefetched
// to LDS to break the dependent-load chain; h row reads coalesced (1 KB).
// ---------------------------------------------------------------------------
#define AGG_CAP 512

__global__ __launch_bounds__(256) void aggregate(const int* __restrict__ src_sorted,
                                                 const float* __restrict__ w_sorted,
                                                 const float* __restrict__ h,
                                                 const int* __restrict__ row_start,
                                                 const int* __restrict__ count,
                                                 const float* __restrict__ bias,
                                                 float* __restrict__ out) {
    __shared__ int sids[AGG_CAP];
    const int n = blockIdx.x;
    const int t = threadIdx.x;
    const int hh = t >> 5;
    const int start = row_start[n];
    const int cnt = count[n];
    float acc = 0.f, den = 0.f;
    for (int base = 0; base < cnt; base += AGG_CAP) {
        int m = min(AGG_CAP, cnt - base);
        __syncthreads();
        for (int i = t; i < m; i += 256) sids[i] = src_sorted[start + base + i];
        __syncthreads();
        const float* wrow = w_sorted + (size_t)(start + base) * 8 + hh;
#pragma unroll 4
        for (int i = 0; i < m; ++i) {
            float w = wrow[(size_t)i * 8];
            den += w;
            acc += w * h[(size_t)sids[i] * C_OUT + t];
        }
    }
    out[(size_t)n * C_OUT + t] = acc / (den + EPS_F) + bias[t];
}

// ---------------------------------------------------------------------------
extern "C" void kernel_launch(void* const* d_in, const int* in_sizes, int n_in,
                              void* d_out, int out_size, void* d_ws, size_t ws_size,
                              hipStream_t stream) {
    const float* x     = (const float*)d_in[0];
    const int*   eidx  = (const int*)d_in[1];
    const float* W     = (const float*)d_in[2];
    const float* a_src = (const float*)d_in[3];
    const float* a_dst = (const float*)d_in[4];
    const float* bias  = (const float*)d_in[5];
    float* out = (float*)d_out;

    const int* src = eidx;
    const int* dst = eidx + N_EDGES;

    char* p = (char*)d_ws;
    auto carve = [&](size_t bytes) {
        char* r = p;
        p += (bytes + 255) & ~(size_t)255;
        return r;
    };
    float* h          = (float*)carve((size_t)N_NODES * C_OUT * 4);     // 40.96 MB
    float* s_src      = (float*)carve((size_t)N_NODES * HEADS * 4);     // 1.28 MB
    float* s_dst      = (float*)carve((size_t)N_NODES * HEADS * 4);     // 1.28 MB
    float* w_sorted   = (float*)carve((size_t)N_EDGES * HEADS * 4);     // 20.48 MB
    int*   src_sorted = (int*)carve((size_t)N_EDGES * 4);               // 2.56 MB
    int*   count      = (int*)carve((size_t)N_NODES * 4);
    int*   row_start  = (int*)carve((size_t)N_NODES * 4);
    int*   cursor     = (int*)carve((size_t)N_NODES * 4);
    unsigned short* Bp_hi = (unsigned short*)carve((size_t)16 * 256 * 32 * 2);  // 256 KB
    unsigned short* Bp_lo = (unsigned short*)carve((size_t)16 * 256 * 32 * 2);

    hipMemsetAsync(count, 0, (size_t)N_NODES * 4, stream);

    pack_W<<<512, 256, 0, stream>>>(W, Bp_hi, Bp_lo);
    gemm_mfma<<<N_NODES / 64, 256, 0, stream>>>(x, Bp_hi, Bp_lo, h);
    attn_scores<<<N_NODES / 8, 256, 0, stream>>>(h, a_src, a_dst, s_src, s_dst);
    count_edges<<<N_EDGES / 256, 256, 0, stream>>>(dst, count);
    scan_counts<<<1, 1024, 0, stream>>>(count, row_start, cursor);
    scatter_edges<<<N_EDGES / 256, 256, 0, stream>>>(src, dst, s_src, s_dst, cursor,
                                                     src_sorted, w_sorted);
    aggregate<<<N_NODES, 256, 0, stream>>>(src_sorted, w_sorted, h, row_start, count, bias, out);
}

// Round 3
// 351.881 us; speedup vs baseline: 3.2016x; 1.1437x over previous
//
#include <hip/hip_runtime.h>
#include <hip/hip_bf16.h>
#include <math.h>
#include <stdint.h>

#define N_NODES 40000
#define N_EDGES 640000
#define F_IN    512
#define F_OUT   32
#define HEADS   8
#define C_OUT   (HEADS * F_OUT)   // 256
#define NEG_SLOPE 0.2f
#define EPS_F   1e-16f

typedef __attribute__((ext_vector_type(8))) short short8;
typedef __attribute__((ext_vector_type(4))) short short4v;
typedef __attribute__((ext_vector_type(4))) float float4v;

// round-to-nearest-even fp32 -> bf16 split: f ~= hi + lo (both bf16)
__device__ __forceinline__ void bf16split(float f, unsigned short& hi, unsigned short& lo) {
    unsigned u = __float_as_uint(f);
    unsigned short h = (unsigned short)((u + 0x7FFF + ((u >> 16) & 1)) >> 16);
    float hf = __uint_as_float(((unsigned)h) << 16);
    float r = f - hf;
    unsigned v = __float_as_uint(r);
    lo = (unsigned short)((v + 0x7FFF + ((v >> 16) & 1)) >> 16);
    hi = h;
}

__device__ __forceinline__ unsigned short f2bf(float f) {
    unsigned u = __float_as_uint(f);
    return (unsigned short)((u + 0x7FFF + ((u >> 16) & 1)) >> 16);
}

// ---------------------------------------------------------------------------
// K0: pack W[H][F_IN][F_OUT] -> Bp_hi/lo [kt=16][c=256][kk=32] bf16
// ---------------------------------------------------------------------------
__global__ __launch_bounds__(256) void pack_W(const float* __restrict__ W,
                                              unsigned short* __restrict__ Bp_hi,
                                              unsigned short* __restrict__ Bp_lo) {
    int tid = blockIdx.x * 256 + threadIdx.x;
    int c = tid >> 9;
    int k = tid & 511;
    int hh = c >> 5, f = c & 31;
    float v = W[hh * (F_IN * F_OUT) + k * F_OUT + f];
    unsigned short hi, lo;
    bf16split(v, hi, lo);
    int out = (k >> 5) * (256 * 32) + c * 32 + (k & 31);
    Bp_hi[out] = hi;
    Bp_lo[out] = lo;
}

// ---------------------------------------------------------------------------
// K1: MFMA projection GEMM, split-precision bf16 (3 MFMA terms ~ fp32 acc).
// Tile 64x256, K-step 32, 4 waves. Epilogue writes h (fp32) and h16 (bf16).
// ---------------------------------------------------------------------------
#define A_STRIDE 40
#define B_STRIDE 40

__global__ __launch_bounds__(256) void gemm_mfma(const float* __restrict__ x,
                                                 const unsigned short* __restrict__ Bp_hi,
                                                 const unsigned short* __restrict__ Bp_lo,
                                                 float* __restrict__ h,
                                                 unsigned short* __restrict__ h16) {
    __shared__ unsigned short As_hi[64 * A_STRIDE];
    __shared__ unsigned short As_lo[64 * A_STRIDE];
    __shared__ unsigned short Bs_hi[256 * B_STRIDE];
    __shared__ unsigned short Bs_lo[256 * B_STRIDE];

    const int t = threadIdx.x;
    const int wave = t >> 6, lane = t & 63;
    const int lm = lane & 15;
    const int lq = lane >> 4;
    const int n0 = blockIdx.x * 64;

    float4v acc[4][4];
#pragma unroll
    for (int i = 0; i < 4; ++i)
#pragma unroll
        for (int j = 0; j < 4; ++j) acc[i][j] = (float4v){0.f, 0.f, 0.f, 0.f};

    for (int kt = 0; kt < 16; ++kt) {
        __syncthreads();
#pragma unroll
        for (int l = 0; l < 2; ++l) {
            int j = t + l * 256;
            int row = j >> 3, q = j & 7;
            float4 v = *(const float4*)&x[(size_t)(n0 + row) * F_IN + kt * 32 + q * 4];
            unsigned short h0, h1, h2, h3, l0, l1, l2, l3;
            bf16split(v.x, h0, l0); bf16split(v.y, h1, l1);
            bf16split(v.z, h2, l2); bf16split(v.w, h3, l3);
            int off = row * A_STRIDE + q * 4;
            *(short4v*)&As_hi[off] = (short4v){(short)h0, (short)h1, (short)h2, (short)h3};
            *(short4v*)&As_lo[off] = (short4v){(short)l0, (short)l1, (short)l2, (short)l3};
        }
        const uint4* gb_hi = (const uint4*)&Bp_hi[(size_t)kt * 256 * 32];
        const uint4* gb_lo = (const uint4*)&Bp_lo[(size_t)kt * 256 * 32];
#pragma unroll
        for (int l = 0; l < 4; ++l) {
            int j = t + l * 256;
            int c = j >> 2, kk = (j & 3) * 8;
            *(uint4*)&Bs_hi[c * B_STRIDE + kk] = gb_hi[j];
            *(uint4*)&Bs_lo[c * B_STRIDE + kk] = gb_lo[j];
        }
        __syncthreads();

        short8 a_hi[4], a_lo[4], b_hi[4], b_lo[4];
#pragma unroll
        for (int mi = 0; mi < 4; ++mi) {
            int off = (mi * 16 + lm) * A_STRIDE + lq * 8;
            a_hi[mi] = *(const short8*)&As_hi[off];
            a_lo[mi] = *(const short8*)&As_lo[off];
        }
#pragma unroll
        for (int ni = 0; ni < 4; ++ni) {
            int off = (wave * 64 + ni * 16 + lm) * B_STRIDE + lq * 8;
            b_hi[ni] = *(const short8*)&Bs_hi[off];
            b_lo[ni] = *(const short8*)&Bs_lo[off];
        }
#pragma unroll
        for (int mi = 0; mi < 4; ++mi)
#pragma unroll
            for (int ni = 0; ni < 4; ++ni) {
                acc[mi][ni] = __builtin_amdgcn_mfma_f32_16x16x32_bf16(a_hi[mi], b_hi[ni], acc[mi][ni], 0, 0, 0);
                acc[mi][ni] = __builtin_amdgcn_mfma_f32_16x16x32_bf16(a_lo[mi], b_hi[ni], acc[mi][ni], 0, 0, 0);
                acc[mi][ni] = __builtin_amdgcn_mfma_f32_16x16x32_bf16(a_hi[mi], b_lo[ni], acc[mi][ni], 0, 0, 0);
            }
    }
#pragma unroll
    for (int mi = 0; mi < 4; ++mi)
#pragma unroll
        for (int ni = 0; ni < 4; ++ni)
#pragma unroll
            for (int r = 0; r < 4; ++r) {
                int row = n0 + mi * 16 + lq * 4 + r;
                int col = wave * 64 + ni * 16 + lm;
                float v = acc[mi][ni][r];
                h[(size_t)row * C_OUT + col] = v;
                h16[(size_t)row * C_OUT + col] = f2bf(v);
            }
}

// ---------------------------------------------------------------------------
// K2: attention score dots (fp32 h)
// ---------------------------------------------------------------------------
__global__ __launch_bounds__(256) void attn_scores(const float* __restrict__ h,
                                                   const float* __restrict__ a_src,
                                                   const float* __restrict__ a_dst,
                                                   float* __restrict__ s_src,
                                                   float* __restrict__ s_dst) {
    const int t = threadIdx.x;
    const int g = t >> 5;
    const int f = t & 31;
    const int n = blockIdx.x * 8 + g;
#pragma unroll
    for (int hh = 0; hh < HEADS; ++hh) {
        float hv = h[(size_t)n * C_OUT + hh * F_OUT + f];
        float vs = hv * a_src[hh * F_OUT + f];
        float vd = hv * a_dst[hh * F_OUT + f];
#pragma unroll
        for (int m = 16; m >= 1; m >>= 1) {
            vs += __shfl_xor(vs, m, 64);
            vd += __shfl_xor(vd, m, 64);
        }
        if (f == 0) {
            s_src[n * HEADS + hh] = vs;
            s_dst[n * HEADS + hh] = vd;
        }
    }
}

// ---------------------------------------------------------------------------
// K3: per-dst in-degree counts
// ---------------------------------------------------------------------------
__global__ __launch_bounds__(256) void count_edges(const int* __restrict__ dst,
                                                   int* __restrict__ count) {
    int e = blockIdx.x * 256 + threadIdx.x;
    atomicAdd(&count[dst[e]], 1);
}

// ---------------------------------------------------------------------------
// K4a: 40-block local exclusive scan (1000 elements/block) -> row_excl,
// cursor (copy), and per-block totals.
// ---------------------------------------------------------------------------
__global__ __launch_bounds__(1024) void scan_local(const int* __restrict__ count,
                                                   int* __restrict__ row_excl,
                                                   int* __restrict__ cursor,
                                                   int* __restrict__ btot) {
    __shared__ int woff[16];
    __shared__ int tot_s;
    const int b = blockIdx.x, t = threadIdx.x;
    const int lane = t & 63, wid = t >> 6;
    const int i = b * 1000 + t;
    int v = (t < 1000) ? count[i] : 0;
    int inc = v;
#pragma unroll
    for (int d = 1; d < 64; d <<= 1) {
        int u = __shfl_up(inc, d, 64);
        if (lane >= d) inc += u;
    }
    if (lane == 63) woff[wid] = inc;
    __syncthreads();
    if (t < 16) {
        int s = woff[t];
        int sc = s;
#pragma unroll
        for (int d = 1; d < 16; d <<= 1) {
            int u = __shfl_up(sc, d, 64);
            if (t >= d) sc += u;
        }
        woff[t] = sc - s;
        if (t == 15) tot_s = sc;
    }
    __syncthreads();
    int excl = woff[wid] + inc - v;
    if (t < 1000) { row_excl[i] = excl; cursor[i] = excl; }
    if (t == 0) btot[b] = tot_s;
}

// K4b: exclusive scan of the 40 block totals -> boff
__global__ __launch_bounds__(64) void scan_tots(const int* __restrict__ btot,
                                                int* __restrict__ boff) {
    const int t = threadIdx.x;
    int v = (t < 40) ? btot[t] : 0;
    int inc = v;
#pragma unroll
    for (int d = 1; d < 64; d <<= 1) {
        int u = __shfl_up(inc, d, 64);
        if (t >= d) inc += u;
    }
    if (t < 40) boff[t] = inc - v;
}

// ---------------------------------------------------------------------------
// K5: scatter. exp(leaky(e)) recomputed (no global max-shift: alpha is
// shift-invariant up to the +1e-16 eps); payload written dst-sorted.
// Global position = local cursor + boff[d/1000].
// ---------------------------------------------------------------------------
__global__ __launch_bounds__(256) void scatter_edges(const int* __restrict__ src,
                                                     const int* __restrict__ dst,
                                                     const float* __restrict__ s_src,
                                                     const float* __restrict__ s_dst,
                                                     int* __restrict__ cursor,
                                                     const int* __restrict__ boff,
                                                     int* __restrict__ src_sorted,
                                                     float* __restrict__ w_sorted) {
    int e = blockIdx.x * 256 + threadIdx.x;
    int s = src[e], d = dst[e];
    const float4* ps = (const float4*)(s_src + s * 8);
    const float4* pd = (const float4*)(s_dst + d * 8);
    float4 a0 = ps[0], a1 = ps[1];
    float4 b0 = pd[0], b1 = pd[1];
    float v[8] = {a0.x + b0.x, a0.y + b0.y, a0.z + b0.z, a0.w + b0.w,
                  a1.x + b1.x, a1.y + b1.y, a1.z + b1.z, a1.w + b1.w};
#pragma unroll
    for (int i = 0; i < 8; ++i) {
        float lv = v[i] >= 0.f ? v[i] : NEG_SLOPE * v[i];
        v[i] = __expf(lv);
    }
    int pos = atomicAdd(&cursor[d], 1) + boff[d / 1000];
    src_sorted[pos] = s;
    float4* po = (float4*)(w_sorted + (size_t)pos * 8);
    po[0] = make_float4(v[0], v[1], v[2], v[3]);
    po[1] = make_float4(v[4], v[5], v[6], v[7]);
}

// ---------------------------------------------------------------------------
// K6: per-dst aggregation from bf16 h copy (halves gather bytes). Denominator
// inline; bias fused. Block per node; thread t owns channel t.
// ---------------------------------------------------------------------------
#define AGG_CAP 512

__global__ __launch_bounds__(256) void aggregate(const int* __restrict__ src_sorted,
                                                 const float* __restrict__ w_sorted,
                                                 const unsigned short* __restrict__ h16,
                                                 const int* __restrict__ row_excl,
                                                 const int* __restrict__ boff,
                                                 const int* __restrict__ count,
                                                 const float* __restrict__ bias,
                                                 float* __restrict__ out) {
    __shared__ int sids[AGG_CAP];
    const int n = blockIdx.x;
    const int t = threadIdx.x;
    const int hh = t >> 5;
    const int start = row_excl[n] + boff[n / 1000];
    const int cnt = count[n];
    float acc = 0.f, den = 0.f;
    for (int base = 0; base < cnt; base += AGG_CAP) {
        int m = min(AGG_CAP, cnt - base);
        __syncthreads();
        for (int i = t; i < m; i += 256) sids[i] = src_sorted[start + base + i];
        __syncthreads();
        const float* wrow = w_sorted + (size_t)(start + base) * 8 + hh;
#pragma unroll 4
        for (int i = 0; i < m; ++i) {
            float w = wrow[(size_t)i * 8];
            den += w;
            unsigned hv = h16[(size_t)sids[i] * C_OUT + t];
            acc += w * __uint_as_float(hv << 16);
        }
    }
    out[(size_t)n * C_OUT + t] = acc / (den + EPS_F) + bias[t];
}

// ---------------------------------------------------------------------------
extern "C" void kernel_launch(void* const* d_in, const int* in_sizes, int n_in,
                              void* d_out, int out_size, void* d_ws, size_t ws_size,
                              hipStream_t stream) {
    const float* x     = (const float*)d_in[0];
    const int*   eidx  = (const int*)d_in[1];
    const float* W     = (const float*)d_in[2];
    const float* a_src = (const float*)d_in[3];
    const float* a_dst = (const float*)d_in[4];
    const float* bias  = (const float*)d_in[5];
    float* out = (float*)d_out;

    const int* src = eidx;
    const int* dst = eidx + N_EDGES;

    char* p = (char*)d_ws;
    auto carve = [&](size_t bytes) {
        char* r = p;
        p += (bytes + 255) & ~(size_t)255;
        return r;
    };
    float* h          = (float*)carve((size_t)N_NODES * C_OUT * 4);           // 40.96 MB
    unsigned short* h16 = (unsigned short*)carve((size_t)N_NODES * C_OUT * 2); // 20.48 MB
    float* s_src      = (float*)carve((size_t)N_NODES * HEADS * 4);
    float* s_dst      = (float*)carve((size_t)N_NODES * HEADS * 4);
    float* w_sorted   = (float*)carve((size_t)N_EDGES * HEADS * 4);           // 20.48 MB
    int*   src_sorted = (int*)carve((size_t)N_EDGES * 4);
    int*   count      = (int*)carve((size_t)N_NODES * 4);
    int*   row_excl   = (int*)carve((size_t)N_NODES * 4);
    int*   cursor     = (int*)carve((size_t)N_NODES * 4);
    int*   btot       = (int*)carve(64 * 4);
    int*   boff       = (int*)carve(64 * 4);
    unsigned short* Bp_hi = (unsigned short*)carve((size_t)16 * 256 * 32 * 2);
    unsigned short* Bp_lo = (unsigned short*)carve((size_t)16 * 256 * 32 * 2);

    hipMemsetAsync(count, 0, (size_t)N_NODES * 4, stream);

    pack_W<<<512, 256, 0, stream>>>(W, Bp_hi, Bp_lo);
    gemm_mfma<<<N_NODES / 64, 256, 0, stream>>>(x, Bp_hi, Bp_lo, h, h16);
    attn_scores<<<N_NODES / 8, 256, 0, stream>>>(h, a_src, a_dst, s_src, s_dst);
    count_edges<<<N_EDGES / 256, 256, 0, stream>>>(dst, count);
    scan_local<<<40, 1024, 0, stream>>>(count, row_excl, cursor, btot);
    scan_tots<<<1, 64, 0, stream>>>(btot, boff);
    scatter_edges<<<N_EDGES / 256, 256, 0, stream>>>(src, dst, s_src, s_dst, cursor, boff,
                                                     src_sorted, w_sorted);
    aggregate<<<N_NODES, 256, 0, stream>>>(src_sorted, w_sorted, h16, row_excl, boff,
                                           count, bias, out);
}

// Round 4
// 335.496 us; speedup vs baseline: 3.3580x; 1.0488x over previous
//
#include <hip/hip_runtime.h>
#include <hip/hip_bf16.h>
#include <math.h>
#include <stdint.h>

#define N_NODES 40000
#define N_EDGES 640000
#define F_IN    512
#define F_OUT   32
#define HEADS   8
#define C_OUT   (HEADS * F_OUT)   // 256
#define NEG_SLOPE 0.2f
#define EPS_F   1e-16f

typedef __attribute__((ext_vector_type(8))) short short8;
typedef __attribute__((ext_vector_type(4))) short short4v;
typedef __attribute__((ext_vector_type(4))) float float4v;

// round-to-nearest-even fp32 -> bf16 split: f ~= hi + lo (both bf16)
__device__ __forceinline__ void bf16split(float f, unsigned short& hi, unsigned short& lo) {
    unsigned u = __float_as_uint(f);
    unsigned short h = (unsigned short)((u + 0x7FFF + ((u >> 16) & 1)) >> 16);
    float hf = __uint_as_float(((unsigned)h) << 16);
    float r = f - hf;
    unsigned v = __float_as_uint(r);
    lo = (unsigned short)((v + 0x7FFF + ((v >> 16) & 1)) >> 16);
    hi = h;
}

__device__ __forceinline__ unsigned short f2bf(float f) {
    unsigned u = __float_as_uint(f);
    return (unsigned short)((u + 0x7FFF + ((u >> 16) & 1)) >> 16);
}

__device__ __forceinline__ float bf2f(unsigned short v) {
    return __uint_as_float(((unsigned)v) << 16);
}

// ---------------------------------------------------------------------------
// K0: pack W[H][F_IN][F_OUT] -> Bp_hi/lo [kt=16][c=256][kk=32] bf16
// ---------------------------------------------------------------------------
__global__ __launch_bounds__(256) void pack_W(const float* __restrict__ W,
                                              unsigned short* __restrict__ Bp_hi,
                                              unsigned short* __restrict__ Bp_lo) {
    int tid = blockIdx.x * 256 + threadIdx.x;
    int c = tid >> 9;
    int k = tid & 511;
    int hh = c >> 5, f = c & 31;
    float v = W[hh * (F_IN * F_OUT) + k * F_OUT + f];
    unsigned short hi, lo;
    bf16split(v, hi, lo);
    int out = (k >> 5) * (256 * 32) + c * 32 + (k & 31);
    Bp_hi[out] = hi;
    Bp_lo[out] = lo;
}

// ---------------------------------------------------------------------------
// K1: MFMA projection GEMM, split-precision bf16 (3 MFMA terms ~ fp32 acc).
// Tile 64x256, K-step 32, 4 waves. Epilogue: writes h16 (bf16) AND computes
// s_src/s_dst via in-register quad reduction (fp32-exact attention path;
// no fp32 h array is ever materialized).
// ---------------------------------------------------------------------------
#define A_STRIDE 40
#define B_STRIDE 40

__global__ __launch_bounds__(256) void gemm_mfma(const float* __restrict__ x,
                                                 const unsigned short* __restrict__ Bp_hi,
                                                 const unsigned short* __restrict__ Bp_lo,
                                                 const float* __restrict__ a_src,
                                                 const float* __restrict__ a_dst,
                                                 unsigned short* __restrict__ h16,
                                                 float* __restrict__ s_src,
                                                 float* __restrict__ s_dst) {
    __shared__ unsigned short As_hi[64 * A_STRIDE];
    __shared__ unsigned short As_lo[64 * A_STRIDE];
    __shared__ unsigned short Bs_hi[256 * B_STRIDE];
    __shared__ unsigned short Bs_lo[256 * B_STRIDE];

    const int t = threadIdx.x;
    const int wave = t >> 6, lane = t & 63;
    const int lm = lane & 15;
    const int lq = lane >> 4;
    const int n0 = blockIdx.x * 64;

    float4v acc[4][4];
#pragma unroll
    for (int i = 0; i < 4; ++i)
#pragma unroll
        for (int j = 0; j < 4; ++j) acc[i][j] = (float4v){0.f, 0.f, 0.f, 0.f};

    for (int kt = 0; kt < 16; ++kt) {
        __syncthreads();
#pragma unroll
        for (int l = 0; l < 2; ++l) {
            int j = t + l * 256;
            int row = j >> 3, q = j & 7;
            float4 v = *(const float4*)&x[(size_t)(n0 + row) * F_IN + kt * 32 + q * 4];
            unsigned short h0, h1, h2, h3, l0, l1, l2, l3;
            bf16split(v.x, h0, l0); bf16split(v.y, h1, l1);
            bf16split(v.z, h2, l2); bf16split(v.w, h3, l3);
            int off = row * A_STRIDE + q * 4;
            *(short4v*)&As_hi[off] = (short4v){(short)h0, (short)h1, (short)h2, (short)h3};
            *(short4v*)&As_lo[off] = (short4v){(short)l0, (short)l1, (short)l2, (short)l3};
        }
        const uint4* gb_hi = (const uint4*)&Bp_hi[(size_t)kt * 256 * 32];
        const uint4* gb_lo = (const uint4*)&Bp_lo[(size_t)kt * 256 * 32];
#pragma unroll
        for (int l = 0; l < 4; ++l) {
            int j = t + l * 256;
            int c = j >> 2, kk = (j & 3) * 8;
            *(uint4*)&Bs_hi[c * B_STRIDE + kk] = gb_hi[j];
            *(uint4*)&Bs_lo[c * B_STRIDE + kk] = gb_lo[j];
        }
        __syncthreads();

        short8 a_hi[4], a_lo[4], b_hi[4], b_lo[4];
#pragma unroll
        for (int mi = 0; mi < 4; ++mi) {
            int off = (mi * 16 + lm) * A_STRIDE + lq * 8;
            a_hi[mi] = *(const short8*)&As_hi[off];
            a_lo[mi] = *(const short8*)&As_lo[off];
        }
#pragma unroll
        for (int ni = 0; ni < 4; ++ni) {
            int off = (wave * 64 + ni * 16 + lm) * B_STRIDE + lq * 8;
            b_hi[ni] = *(const short8*)&Bs_hi[off];
            b_lo[ni] = *(const short8*)&Bs_lo[off];
        }
#pragma unroll
        for (int mi = 0; mi < 4; ++mi)
#pragma unroll
            for (int ni = 0; ni < 4; ++ni) {
                acc[mi][ni] = __builtin_amdgcn_mfma_f32_16x16x32_bf16(a_hi[mi], b_hi[ni], acc[mi][ni], 0, 0, 0);
                acc[mi][ni] = __builtin_amdgcn_mfma_f32_16x16x32_bf16(a_lo[mi], b_hi[ni], acc[mi][ni], 0, 0, 0);
                acc[mi][ni] = __builtin_amdgcn_mfma_f32_16x16x32_bf16(a_hi[mi], b_lo[ni], acc[mi][ni], 0, 0, 0);
            }
    }

    // ---- epilogue 1: h16 stores (C layout: col=lm, row=lq*4+r) ----
#pragma unroll
    for (int mi = 0; mi < 4; ++mi)
#pragma unroll
        for (int ni = 0; ni < 4; ++ni)
#pragma unroll
            for (int r = 0; r < 4; ++r) {
                int row = n0 + mi * 16 + lq * 4 + r;
                int col = wave * 64 + ni * 16 + lm;
                h16[(size_t)row * C_OUT + col] = f2bf(acc[mi][ni][r]);
            }

    // ---- epilogue 2: fused attention scores (fp32-exact) ----
    // wave owns cols [wave*64, wave*64+64) = heads h0=2*wave, h1=2*wave+1.
    const int h0 = wave * 2, h1 = wave * 2 + 1;
    const float as00 = a_src[h0 * 32 + lm],      as01 = a_src[h0 * 32 + 16 + lm];
    const float as10 = a_src[h1 * 32 + lm],      as11 = a_src[h1 * 32 + 16 + lm];
    const float ad00 = a_dst[h0 * 32 + lm],      ad01 = a_dst[h0 * 32 + 16 + lm];
    const float ad10 = a_dst[h1 * 32 + lm],      ad11 = a_dst[h1 * 32 + 16 + lm];
#pragma unroll
    for (int mi = 0; mi < 4; ++mi)
#pragma unroll
        for (int r = 0; r < 4; ++r) {
            float ps0 = acc[mi][0][r] * as00 + acc[mi][1][r] * as01;
            float ps1 = acc[mi][2][r] * as10 + acc[mi][3][r] * as11;
            float pd0 = acc[mi][0][r] * ad00 + acc[mi][1][r] * ad01;
            float pd1 = acc[mi][2][r] * ad10 + acc[mi][3][r] * ad11;
#pragma unroll
            for (int m = 1; m < 16; m <<= 1) {
                ps0 += __shfl_xor(ps0, m, 64);
                ps1 += __shfl_xor(ps1, m, 64);
                pd0 += __shfl_xor(pd0, m, 64);
                pd1 += __shfl_xor(pd1, m, 64);
            }
            if (lm == 0) {
                int row = n0 + mi * 16 + lq * 4 + r;
                s_src[row * 8 + h0] = ps0;
                s_src[row * 8 + h1] = ps1;
                s_dst[row * 8 + h0] = pd0;
                s_dst[row * 8 + h1] = pd1;
            }
        }
}

// ---------------------------------------------------------------------------
// K3: per-dst in-degree counts
// ---------------------------------------------------------------------------
__global__ __launch_bounds__(256) void count_edges(const int* __restrict__ dst,
                                                   int* __restrict__ count) {
    int e = blockIdx.x * 256 + threadIdx.x;
    atomicAdd(&count[dst[e]], 1);
}

// ---------------------------------------------------------------------------
// K4a: 40-block local exclusive scan (1000/block) + per-block totals
// ---------------------------------------------------------------------------
__global__ __launch_bounds__(1024) void scan_local(const int* __restrict__ count,
                                                   int* __restrict__ row_excl,
                                                   int* __restrict__ cursor,
                                                   int* __restrict__ btot) {
    __shared__ int woff[16];
    __shared__ int tot_s;
    const int b = blockIdx.x, t = threadIdx.x;
    const int lane = t & 63, wid = t >> 6;
    const int i = b * 1000 + t;
    int v = (t < 1000) ? count[i] : 0;
    int inc = v;
#pragma unroll
    for (int d = 1; d < 64; d <<= 1) {
        int u = __shfl_up(inc, d, 64);
        if (lane >= d) inc += u;
    }
    if (lane == 63) woff[wid] = inc;
    __syncthreads();
    if (t < 16) {
        int s = woff[t];
        int sc = s;
#pragma unroll
        for (int d = 1; d < 16; d <<= 1) {
            int u = __shfl_up(sc, d, 64);
            if (t >= d) sc += u;
        }
        woff[t] = sc - s;
        if (t == 15) tot_s = sc;
    }
    __syncthreads();
    int excl = woff[wid] + inc - v;
    if (t < 1000) { row_excl[i] = excl; cursor[i] = excl; }
    if (t == 0) btot[b] = tot_s;
}

// K4b: exclusive scan of the 40 block totals -> boff
__global__ __launch_bounds__(64) void scan_tots(const int* __restrict__ btot,
                                                int* __restrict__ boff) {
    const int t = threadIdx.x;
    int v = (t < 40) ? btot[t] : 0;
    int inc = v;
#pragma unroll
    for (int d = 1; d < 64; d <<= 1) {
        int u = __shfl_up(inc, d, 64);
        if (t >= d) inc += u;
    }
    if (t < 40) boff[t] = inc - v;
}

// ---------------------------------------------------------------------------
// K5: slim scatter — only the dst-sorted src ids (4 B/edge). Attention
// weights are recomputed in aggregate from s_src/s_dst (L2-resident).
// ---------------------------------------------------------------------------
__global__ __launch_bounds__(256) void scatter_edges(const int* __restrict__ src,
                                                     const int* __restrict__ dst,
                                                     int* __restrict__ cursor,
                                                     const int* __restrict__ boff,
                                                     int* __restrict__ src_sorted) {
    int e = blockIdx.x * 256 + threadIdx.x;
    int s = src[e], d = dst[e];
    int pos = atomicAdd(&cursor[d], 1) + boff[d / 1000];
    src_sorted[pos] = s;
}

// ---------------------------------------------------------------------------
// K6: aggregation. One WAVE per node (4 nodes / 256-block); lane owns 4
// channels (8 B h16 load -> full-wave 512 B per edge). 4-edge unroll for
// ILP. w = exp(leaky(s_src[s]+s_dst[n])) recomputed inline (fp32 exact,
// den and numerator consistent). No max-shift (alpha shift-invariant up
// to +1e-16 eps).
// ---------------------------------------------------------------------------
__global__ __launch_bounds__(256) void aggregate(const int* __restrict__ src_sorted,
                                                 const unsigned short* __restrict__ h16,
                                                 const float* __restrict__ s_src,
                                                 const float* __restrict__ s_dst,
                                                 const int* __restrict__ row_excl,
                                                 const int* __restrict__ boff,
                                                 const int* __restrict__ count,
                                                 const float* __restrict__ bias,
                                                 float* __restrict__ out) {
    const int t = threadIdx.x;
    const int wave = t >> 6, lane = t & 63;
    const int n = blockIdx.x * 4 + wave;
    const int ch0 = lane * 4;          // 4 channels per lane
    const int hh = lane >> 3;          // head of those channels
    const int start = row_excl[n] + boff[n / 1000];
    const int cnt = count[n];
    const float sd = s_dst[n * 8 + hh];

    float a0 = 0.f, a1 = 0.f, a2 = 0.f, a3 = 0.f, den = 0.f;

    for (int base = 0; base < cnt; base += 4) {
        int rem = cnt - base;
        int idx = start + base;
        int s0 = src_sorted[idx];
        int s1 = (rem > 1) ? src_sorted[idx + 1] : 0;
        int s2 = (rem > 2) ? src_sorted[idx + 2] : 0;
        int s3 = (rem > 3) ? src_sorted[idx + 3] : 0;

        float e0 = s_src[s0 * 8 + hh] + sd;
        float e1 = s_src[s1 * 8 + hh] + sd;
        float e2 = s_src[s2 * 8 + hh] + sd;
        float e3 = s_src[s3 * 8 + hh] + sd;
        e0 = e0 >= 0.f ? e0 : NEG_SLOPE * e0;
        e1 = e1 >= 0.f ? e1 : NEG_SLOPE * e1;
        e2 = e2 >= 0.f ? e2 : NEG_SLOPE * e2;
        e3 = e3 >= 0.f ? e3 : NEG_SLOPE * e3;
        float w0 = __expf(e0);
        float w1 = (rem > 1) ? __expf(e1) : 0.f;
        float w2 = (rem > 2) ? __expf(e2) : 0.f;
        float w3 = (rem > 3) ? __expf(e3) : 0.f;

        short4v v0 = *(const short4v*)&h16[(size_t)s0 * C_OUT + ch0];
        short4v v1 = *(const short4v*)&h16[(size_t)s1 * C_OUT + ch0];
        short4v v2 = *(const short4v*)&h16[(size_t)s2 * C_OUT + ch0];
        short4v v3 = *(const short4v*)&h16[(size_t)s3 * C_OUT + ch0];

        a0 += w0 * bf2f((unsigned short)v0[0]) + w1 * bf2f((unsigned short)v1[0])
            + w2 * bf2f((unsigned short)v2[0]) + w3 * bf2f((unsigned short)v3[0]);
        a1 += w0 * bf2f((unsigned short)v0[1]) + w1 * bf2f((unsigned short)v1[1])
            + w2 * bf2f((unsigned short)v2[1]) + w3 * bf2f((unsigned short)v3[1]);
        a2 += w0 * bf2f((unsigned short)v0[2]) + w1 * bf2f((unsigned short)v1[2])
            + w2 * bf2f((unsigned short)v2[2]) + w3 * bf2f((unsigned short)v3[2]);
        a3 += w0 * bf2f((unsigned short)v0[3]) + w1 * bf2f((unsigned short)v1[3])
            + w2 * bf2f((unsigned short)v2[3]) + w3 * bf2f((unsigned short)v3[3]);
        den += w0 + w1 + w2 + w3;
    }

    float inv = 1.0f / (den + EPS_F);
    float4 b4 = *(const float4*)&bias[ch0];
    float4 o;
    o.x = a0 * inv + b4.x;
    o.y = a1 * inv + b4.y;
    o.z = a2 * inv + b4.z;
    o.w = a3 * inv + b4.w;
    *(float4*)&out[(size_t)n * C_OUT + ch0] = o;
}

// ---------------------------------------------------------------------------
extern "C" void kernel_launch(void* const* d_in, const int* in_sizes, int n_in,
                              void* d_out, int out_size, void* d_ws, size_t ws_size,
                              hipStream_t stream) {
    const float* x     = (const float*)d_in[0];
    const int*   eidx  = (const int*)d_in[1];
    const float* W     = (const float*)d_in[2];
    const float* a_src = (const float*)d_in[3];
    const float* a_dst = (const float*)d_in[4];
    const float* bias  = (const float*)d_in[5];
    float* out = (float*)d_out;

    const int* src = eidx;
    const int* dst = eidx + N_EDGES;

    char* p = (char*)d_ws;
    auto carve = [&](size_t bytes) {
        char* r = p;
        p += (bytes + 255) & ~(size_t)255;
        return r;
    };
    unsigned short* h16 = (unsigned short*)carve((size_t)N_NODES * C_OUT * 2); // 20.48 MB
    float* s_src      = (float*)carve((size_t)N_NODES * HEADS * 4);            // 1.28 MB
    float* s_dst      = (float*)carve((size_t)N_NODES * HEADS * 4);            // 1.28 MB
    int*   src_sorted = (int*)carve((size_t)N_EDGES * 4);                      // 2.56 MB
    int*   count      = (int*)carve((size_t)N_NODES * 4);
    int*   row_excl   = (int*)carve((size_t)N_NODES * 4);
    int*   cursor     = (int*)carve((size_t)N_NODES * 4);
    int*   btot       = (int*)carve(64 * 4);
    int*   boff       = (int*)carve(64 * 4);
    unsigned short* Bp_hi = (unsigned short*)carve((size_t)16 * 256 * 32 * 2);
    unsigned short* Bp_lo = (unsigned short*)carve((size_t)16 * 256 * 32 * 2);

    hipMemsetAsync(count, 0, (size_t)N_NODES * 4, stream);

    pack_W<<<512, 256, 0, stream>>>(W, Bp_hi, Bp_lo);
    gemm_mfma<<<N_NODES / 64, 256, 0, stream>>>(x, Bp_hi, Bp_lo, a_src, a_dst,
                                                h16, s_src, s_dst);
    count_edges<<<N_EDGES / 256, 256, 0, stream>>>(dst, count);
    scan_local<<<40, 1024, 0, stream>>>(count, row_excl, cursor, btot);
    scan_tots<<<1, 64, 0, stream>>>(btot, boff);
    scatter_edges<<<N_EDGES / 256, 256, 0, stream>>>(src, dst, cursor, boff, src_sorted);
    aggregate<<<N_NODES / 4, 256, 0, stream>>>(src_sorted, h16, s_src, s_dst,
                                               row_excl, boff, count, bias, out);
}

// Round 5
// 303.578 us; speedup vs baseline: 3.7110x; 1.1051x over previous
//
#include <hip/hip_runtime.h>
#include <hip/hip_bf16.h>
#include <math.h>
#include <stdint.h>

#define N_NODES 40000
#define N_EDGES 640000
#define F_IN    512
#define F_OUT   32
#define HEADS   8
#define C_OUT   (HEADS * F_OUT)   // 256
#define NEG_SLOPE 0.2f
#define EPS_F   1e-16f

typedef __attribute__((ext_vector_type(8)))  short  short8;
typedef __attribute__((ext_vector_type(4)))  short  short4v;
typedef __attribute__((ext_vector_type(16))) float  float16v;

// truncating fp32 -> (hi,lo) bf16 split: hi+lo represents f to ~2^-17 rel
__device__ __forceinline__ void splitT(float f, unsigned short& hi, unsigned short& lo) {
    unsigned u = __float_as_uint(f);
    hi = (unsigned short)(u >> 16);
    float r = f - __uint_as_float(u & 0xFFFF0000u);
    lo = (unsigned short)(__float_as_uint(r) >> 16);
}

__device__ __forceinline__ unsigned short f2bf(float f) {
    unsigned u = __float_as_uint(f);
    return (unsigned short)((u + 0x7FFF + ((u >> 16) & 1)) >> 16);
}

// ---------------------------------------------------------------------------
// K0: pack W into per-lane B-fragment layout for mfma_f32_32x32x16_bf16.
// Bp[strip(2)][wc(2)][ktg(32)][ni(2)][lane(64)][j(8)], value =
//   B[k = ktg*16 + (lane>>5)*8 + j][col = strip*128 + wc*64 + ni*32 + (lane&31)]
// where B[k][col] = W[col>>5][k][col&31]. One wave dwordx4 per (kt,ni).
// ---------------------------------------------------------------------------
__global__ __launch_bounds__(256) void pack_W(const float* __restrict__ W,
                                              unsigned short* __restrict__ Bp) {
    int tid = blockIdx.x * 256 + threadIdx.x;   // 131072 total
    int j    = tid & 7;
    int L    = (tid >> 3) & 63;
    int ni   = (tid >> 9) & 1;
    int ktg  = (tid >> 10) & 31;
    int wc   = (tid >> 15) & 1;
    int strip= tid >> 16;
    int k    = ktg * 16 + (L >> 5) * 8 + j;
    int col  = strip * 128 + wc * 64 + ni * 32 + (L & 31);
    int hh = col >> 5, f = col & 31;
    Bp[tid] = f2bf(W[hh * (F_IN * F_OUT) + k * F_OUT + f]);
}

// ---------------------------------------------------------------------------
// K1: MFMA projection GEMM, 32x32x16 bf16, 2-term split ((x_hi+x_lo)*B_hi).
// Block: 4 waves (2x2), tile 128 rows x 128 cols; grid (313, 2). BK=64.
// A staged in LDS (stride 66 shorts = 33 banks -> conflict-free frag reads);
// B fragments loaded register-direct from L2-resident packed buffer.
// Epilogue: h16 stores + fused fp32-exact attention scores.
// ---------------------------------------------------------------------------
#define AS 66   // k-stride in shorts: 64 + 2 pad (33 banks, odd -> bijection)

__global__ __launch_bounds__(256, 3) void gemm_mfma(const float* __restrict__ x,
                                                    const unsigned short* __restrict__ Bp,
                                                    const float* __restrict__ a_src,
                                                    const float* __restrict__ a_dst,
                                                    unsigned short* __restrict__ h16,
                                                    float* __restrict__ s_src,
                                                    float* __restrict__ s_dst) {
    __shared__ unsigned short As_hi[128 * AS];
    __shared__ unsigned short As_lo[128 * AS];

    const int t = threadIdx.x;
    const int wave = t >> 6, L = t & 63;
    const int wr = wave & 1, wc = wave >> 1;
    const int r31 = L & 31, half = L >> 5;
    const int strip = blockIdx.y;
    const int n0 = blockIdx.x * 128;

    float16v acc[2][2];
#pragma unroll
    for (int i = 0; i < 2; ++i)
#pragma unroll
        for (int j = 0; j < 2; ++j)
#pragma unroll
            for (int r = 0; r < 16; ++r) acc[i][j][r] = 0.f;

    const int kcol = (t & 15) * 4;
    const int rbase = t >> 4;

    for (int st = 0; st < 8; ++st) {
        const int kb = st * 64;
        __syncthreads();
        // ---- stage A: 128 rows x 64 k fp32 -> bf16 hi/lo in LDS ----
#pragma unroll
        for (int it = 0; it < 8; ++it) {
            int r = rbase + it * 16;
            int rg = n0 + r; rg = rg < N_NODES ? rg : N_NODES - 1;
            float4 v = *(const float4*)&x[(size_t)rg * F_IN + kb + kcol];
            unsigned short h0, h1, h2, h3, l0, l1, l2, l3;
            splitT(v.x, h0, l0); splitT(v.y, h1, l1);
            splitT(v.z, h2, l2); splitT(v.w, h3, l3);
            int off = r * AS + kcol;
            *(short4v*)&As_hi[off] = (short4v){(short)h0, (short)h1, (short)h2, (short)h3};
            *(short4v*)&As_lo[off] = (short4v){(short)l0, (short)l1, (short)l2, (short)l3};
        }
        __syncthreads();

        // ---- B fragments: register-direct, 8 coalesced dwordx4 per wave ----
        short8 breg[4][2];
#pragma unroll
        for (int kt = 0; kt < 4; ++kt)
#pragma unroll
            for (int ni = 0; ni < 2; ++ni) {
                size_t idx = ((((size_t)(strip * 2 + wc) * 32 + (st * 4 + kt)) * 2 + ni) * 64 + L) * 8;
                breg[kt][ni] = *(const short8*)&Bp[idx];
            }

        // ---- MFMA: 4 k-steps of 16, 2 mi x 2 ni x 2 terms ----
#pragma unroll
        for (int kt = 0; kt < 4; ++kt) {
            short8 ah[2], al[2];
#pragma unroll
            for (int mi = 0; mi < 2; ++mi) {
                int off = (wr * 64 + mi * 32 + r31) * AS + kt * 16 + half * 8;
                ah[mi] = *(const short8*)&As_hi[off];
                al[mi] = *(const short8*)&As_lo[off];
            }
#pragma unroll
            for (int mi = 0; mi < 2; ++mi)
#pragma unroll
                for (int ni = 0; ni < 2; ++ni) {
                    acc[mi][ni] = __builtin_amdgcn_mfma_f32_32x32x16_bf16(ah[mi], breg[kt][ni], acc[mi][ni], 0, 0, 0);
                    acc[mi][ni] = __builtin_amdgcn_mfma_f32_32x32x16_bf16(al[mi], breg[kt][ni], acc[mi][ni], 0, 0, 0);
                }
        }
    }

    // ---- epilogue 1: h16 stores ----
    // C/D layout (32x32): col = lane&31, row = (reg&3) + 8*(reg>>2) + 4*half
#pragma unroll
    for (int mi = 0; mi < 2; ++mi)
#pragma unroll
        for (int ni = 0; ni < 2; ++ni) {
            int colb = strip * 128 + wc * 64 + ni * 32 + r31;
#pragma unroll
            for (int r = 0; r < 16; ++r) {
                int row = n0 + wr * 64 + mi * 32 + (r & 3) + 8 * (r >> 2) + 4 * half;
                if (row < N_NODES)
                    h16[(size_t)row * C_OUT + colb] = f2bf(acc[mi][ni][r]);
            }
        }

    // ---- epilogue 2: fused attention scores (fp32-exact) ----
    // ni-frag covers exactly one head: hh = strip*4 + wc*2 + ni
#pragma unroll
    for (int ni = 0; ni < 2; ++ni) {
        int hh = strip * 4 + wc * 2 + ni;
        float af = a_src[hh * 32 + r31];
        float df = a_dst[hh * 32 + r31];
#pragma unroll
        for (int mi = 0; mi < 2; ++mi)
#pragma unroll
            for (int r = 0; r < 16; ++r) {
                float v = acc[mi][ni][r];
                float vs = v * af;
                float vd = v * df;
#pragma unroll
                for (int m = 1; m < 32; m <<= 1) {
                    vs += __shfl_xor(vs, m, 64);
                    vd += __shfl_xor(vd, m, 64);
                }
                if (r31 == 0) {
                    int row = n0 + wr * 64 + mi * 32 + (r & 3) + 8 * (r >> 2) + 4 * half;
                    if (row < N_NODES) {
                        s_src[row * 8 + hh] = vs;
                        s_dst[row * 8 + hh] = vd;
                    }
                }
            }
    }
}

// ---------------------------------------------------------------------------
// K3: per-dst in-degree counts
// ---------------------------------------------------------------------------
__global__ __launch_bounds__(256) void count_edges(const int* __restrict__ dst,
                                                   int* __restrict__ count) {
    int e = blockIdx.x * 256 + threadIdx.x;
    atomicAdd(&count[dst[e]], 1);
}

// ---------------------------------------------------------------------------
// K4a: 40-block local exclusive scan (1000/block) + per-block totals
// ---------------------------------------------------------------------------
__global__ __launch_bounds__(1024) void scan_local(const int* __restrict__ count,
                                                   int* __restrict__ row_excl,
                                                   int* __restrict__ cursor,
                                                   int* __restrict__ btot) {
    __shared__ int woff[16];
    __shared__ int tot_s;
    const int b = blockIdx.x, t = threadIdx.x;
    const int lane = t & 63, wid = t >> 6;
    const int i = b * 1000 + t;
    int v = (t < 1000) ? count[i] : 0;
    int inc = v;
#pragma unroll
    for (int d = 1; d < 64; d <<= 1) {
        int u = __shfl_up(inc, d, 64);
        if (lane >= d) inc += u;
    }
    if (lane == 63) woff[wid] = inc;
    __syncthreads();
    if (t < 16) {
        int s = woff[t];
        int sc = s;
#pragma unroll
        for (int d = 1; d < 16; d <<= 1) {
            int u = __shfl_up(sc, d, 64);
            if (t >= d) sc += u;
        }
        woff[t] = sc - s;
        if (t == 15) tot_s = sc;
    }
    __syncthreads();
    int excl = woff[wid] + inc - v;
    if (t < 1000) { row_excl[i] = excl; cursor[i] = excl; }
    if (t == 0) btot[b] = tot_s;
}

// K4b: exclusive scan of the 40 block totals -> boff
__global__ __launch_bounds__(64) void scan_tots(const int* __restrict__ btot,
                                                int* __restrict__ boff) {
    const int t = threadIdx.x;
    int v = (t < 40) ? btot[t] : 0;
    int inc = v;
#pragma unroll
    for (int d = 1; d < 64; d <<= 1) {
        int u = __shfl_up(inc, d, 64);
        if (t >= d) inc += u;
    }
    if (t < 40) boff[t] = inc - v;
}

// ---------------------------------------------------------------------------
// K5: slim scatter — only the dst-sorted src ids (4 B/edge).
// ---------------------------------------------------------------------------
__global__ __launch_bounds__(256) void scatter_edges(const int* __restrict__ src,
                                                     const int* __restrict__ dst,
                                                     int* __restrict__ cursor,
                                                     const int* __restrict__ boff,
                                                     int* __restrict__ src_sorted) {
    int e = blockIdx.x * 256 + threadIdx.x;
    int s = src[e], d = dst[e];
    int pos = atomicAdd(&cursor[d], 1) + boff[d / 1000];
    src_sorted[pos] = s;
}

// ---------------------------------------------------------------------------
// K6: aggregation. One WAVE per node; lane owns 4 channels; 4-edge unroll.
// w = exp(leaky(s_src[s]+s_dst[n])) recomputed inline (fp32 exact).
// ---------------------------------------------------------------------------
__global__ __launch_bounds__(256) void aggregate(const int* __restrict__ src_sorted,
                                                 const unsigned short* __restrict__ h16,
                                                 const float* __restrict__ s_src,
                                                 const float* __restrict__ s_dst,
                                                 const int* __restrict__ row_excl,
                                                 const int* __restrict__ boff,
                                                 const int* __restrict__ count,
                                                 const float* __restrict__ bias,
                                                 float* __restrict__ out) {
    const int t = threadIdx.x;
    const int wave = t >> 6, lane = t & 63;
    const int n = blockIdx.x * 4 + wave;
    const int ch0 = lane * 4;
    const int hh = lane >> 3;
    const int start = row_excl[n] + boff[n / 1000];
    const int cnt = count[n];
    const float sd = s_dst[n * 8 + hh];

    float a0 = 0.f, a1 = 0.f, a2 = 0.f, a3 = 0.f, den = 0.f;

    for (int base = 0; base < cnt; base += 4) {
        int rem = cnt - base;
        int idx = start + base;
        int s0 = src_sorted[idx];
        int s1 = (rem > 1) ? src_sorted[idx + 1] : 0;
        int s2 = (rem > 2) ? src_sorted[idx + 2] : 0;
        int s3 = (rem > 3) ? src_sorted[idx + 3] : 0;

        float e0 = s_src[s0 * 8 + hh] + sd;
        float e1 = s_src[s1 * 8 + hh] + sd;
        float e2 = s_src[s2 * 8 + hh] + sd;
        float e3 = s_src[s3 * 8 + hh] + sd;
        e0 = e0 >= 0.f ? e0 : NEG_SLOPE * e0;
        e1 = e1 >= 0.f ? e1 : NEG_SLOPE * e1;
        e2 = e2 >= 0.f ? e2 : NEG_SLOPE * e2;
        e3 = e3 >= 0.f ? e3 : NEG_SLOPE * e3;
        float w0 = __expf(e0);
        float w1 = (rem > 1) ? __expf(e1) : 0.f;
        float w2 = (rem > 2) ? __expf(e2) : 0.f;
        float w3 = (rem > 3) ? __expf(e3) : 0.f;

        short4v v0 = *(const short4v*)&h16[(size_t)s0 * C_OUT + ch0];
        short4v v1 = *(const short4v*)&h16[(size_t)s1 * C_OUT + ch0];
        short4v v2 = *(const short4v*)&h16[(size_t)s2 * C_OUT + ch0];
        short4v v3 = *(const short4v*)&h16[(size_t)s3 * C_OUT + ch0];

        auto bf2f = [](short v) { return __uint_as_float(((unsigned)(unsigned short)v) << 16); };
        a0 += w0 * bf2f(v0[0]) + w1 * bf2f(v1[0]) + w2 * bf2f(v2[0]) + w3 * bf2f(v3[0]);
        a1 += w0 * bf2f(v0[1]) + w1 * bf2f(v1[1]) + w2 * bf2f(v2[1]) + w3 * bf2f(v3[1]);
        a2 += w0 * bf2f(v0[2]) + w1 * bf2f(v1[2]) + w2 * bf2f(v2[2]) + w3 * bf2f(v3[2]);
        a3 += w0 * bf2f(v0[3]) + w1 * bf2f(v1[3]) + w2 * bf2f(v2[3]) + w3 * bf2f(v3[3]);
        den += w0 + w1 + w2 + w3;
    }

    float inv = 1.0f / (den + EPS_F);
    float4 b4 = *(const float4*)&bias[ch0];
    float4 o;
    o.x = a0 * inv + b4.x;
    o.y = a1 * inv + b4.y;
    o.z = a2 * inv + b4.z;
    o.w = a3 * inv + b4.w;
    *(float4*)&out[(size_t)n * C_OUT + ch0] = o;
}

// ---------------------------------------------------------------------------
extern "C" void kernel_launch(void* const* d_in, const int* in_sizes, int n_in,
                              void* d_out, int out_size, void* d_ws, size_t ws_size,
                              hipStream_t stream) {
    const float* x     = (const float*)d_in[0];
    const int*   eidx  = (const int*)d_in[1];
    const float* W     = (const float*)d_in[2];
    const float* a_src = (const float*)d_in[3];
    const float* a_dst = (const float*)d_in[4];
    const float* bias  = (const float*)d_in[5];
    float* out = (float*)d_out;

    const int* src = eidx;
    const int* dst = eidx + N_EDGES;

    char* p = (char*)d_ws;
    auto carve = [&](size_t bytes) {
        char* r = p;
        p += (bytes + 255) & ~(size_t)255;
        return r;
    };
    unsigned short* h16 = (unsigned short*)carve((size_t)N_NODES * C_OUT * 2); // 20.48 MB
    float* s_src      = (float*)carve((size_t)N_NODES * HEADS * 4);
    float* s_dst      = (float*)carve((size_t)N_NODES * HEADS * 4);
    int*   src_sorted = (int*)carve((size_t)N_EDGES * 4);
    int*   count      = (int*)carve((size_t)N_NODES * 4);
    int*   row_excl   = (int*)carve((size_t)N_NODES * 4);
    int*   cursor     = (int*)carve((size_t)N_NODES * 4);
    int*   btot       = (int*)carve(64 * 4);
    int*   boff       = (int*)carve(64 * 4);
    unsigned short* Bp = (unsigned short*)carve((size_t)131072 * 2);           // 256 KB

    hipMemsetAsync(count, 0, (size_t)N_NODES * 4, stream);

    pack_W<<<512, 256, 0, stream>>>(W, Bp);
    dim3 ggrid(313, 2);
    gemm_mfma<<<ggrid, 256, 0, stream>>>(x, Bp, a_src, a_dst, h16, s_src, s_dst);
    count_edges<<<N_EDGES / 256, 256, 0, stream>>>(dst, count);
    scan_local<<<40, 1024, 0, stream>>>(count, row_excl, cursor, btot);
    scan_tots<<<1, 64, 0, stream>>>(btot, boff);
    scatter_edges<<<N_EDGES / 256, 256, 0, stream>>>(src, dst, cursor, boff, src_sorted);
    aggregate<<<N_NODES / 4, 256, 0, stream>>>(src_sorted, h16, s_src, s_dst,
                                               row_excl, boff, count, bias, out);
}